// Round 3
// baseline (198.401 us; speedup 1.0000x reference)
//
#include <hip/hip_runtime.h>
#include <hip/hip_bf16.h>
#include <math.h>

typedef unsigned short u16;
typedef __attribute__((ext_vector_type(8))) short bf16x8_t;   // 8 bf16 in 4 VGPRs
typedef __attribute__((ext_vector_type(4))) float f32x4_t;
typedef __attribute__((ext_vector_type(4))) int  i32x4_t;

#define SEQ 4096
#define EMB 512
#define HD  64
#define NBATCH 4
// 1/sqrt(512) * log2(e)  (bug-faithful d_k = embed dim 512)
#define C2 0.063758718f

#define SLOT_F 1040           // floats per partial slot: 16*64 o + 16 lsum
#define SLOTS_PER_B 1152      // sum over tiles of chunk counts

__device__ __forceinline__ u16 to_bf(float f) {
    __hip_bfloat16 h = __float2bfloat16(f);
    return __builtin_bit_cast(u16, h);
}

// ---------------------------------------------------------------------------
// Projection: out[g][h] = sum_e in[g][e] * W[h][e] + b[h], g = 0..16383
// z = blockIdx.y: 0 -> Q, 1 -> K, 2 -> V (V written transposed [B][64][S])
// ---------------------------------------------------------------------------
__global__ __launch_bounds__(256)
void proj_kernel(const float* __restrict__ q_in, const float* __restrict__ k_in,
                 const float* __restrict__ v_in,
                 const float* __restrict__ Wq, const float* __restrict__ bq,
                 const float* __restrict__ Wk, const float* __restrict__ bk,
                 const float* __restrict__ Wv, const float* __restrict__ bv,
                 u16* __restrict__ outQ, u16* __restrict__ outK,
                 u16* __restrict__ outVT)
{
    const int z = blockIdx.y;
    const float* in   = (z == 0) ? q_in : (z == 1) ? k_in : v_in;
    const float* W    = (z == 0) ? Wq   : (z == 1) ? Wk   : Wv;
    const float* bias = (z == 0) ? bq   : (z == 1) ? bk   : bv;

    __shared__ u16 A_lds[64][72];
    __shared__ u16 B_lds[64][72];

    const int tid  = threadIdx.x;
    const int lane = tid & 63;
    const int w    = tid >> 6;
    const int l15  = lane & 15;
    const int lg   = lane >> 4;
    const int g0   = blockIdx.x * 64;

    f32x4_t acc[4];
    #pragma unroll
    for (int i = 0; i < 4; ++i)
        #pragma unroll
        for (int j = 0; j < 4; ++j) acc[i][j] = 0.f;

    const int r   = tid >> 2;
    const int seg = tid & 3;

    for (int ec = 0; ec < EMB / 64; ++ec) {
        __syncthreads();
        {
            const float* srcA = in + (size_t)(g0 + r) * EMB + ec * 64 + seg * 16;
            const float* srcB = W  + (size_t)r        * EMB + ec * 64 + seg * 16;
            u16 ta[16], tb[16];
            #pragma unroll
            for (int u = 0; u < 4; ++u) {
                f32x4_t fa = *reinterpret_cast<const f32x4_t*>(srcA + 4 * u);
                f32x4_t fb = *reinterpret_cast<const f32x4_t*>(srcB + 4 * u);
                #pragma unroll
                for (int q = 0; q < 4; ++q) {
                    ta[4 * u + q] = to_bf(fa[q]);
                    tb[4 * u + q] = to_bf(fb[q]);
                }
            }
            *reinterpret_cast<i32x4_t*>(&A_lds[r][seg * 16 + 0]) = *reinterpret_cast<i32x4_t*>(&ta[0]);
            *reinterpret_cast<i32x4_t*>(&A_lds[r][seg * 16 + 8]) = *reinterpret_cast<i32x4_t*>(&ta[8]);
            *reinterpret_cast<i32x4_t*>(&B_lds[r][seg * 16 + 0]) = *reinterpret_cast<i32x4_t*>(&tb[0]);
            *reinterpret_cast<i32x4_t*>(&B_lds[r][seg * 16 + 8]) = *reinterpret_cast<i32x4_t*>(&tb[8]);
        }
        __syncthreads();
        #pragma unroll
        for (int ks = 0; ks < 2; ++ks) {
            bf16x8_t a = *reinterpret_cast<const bf16x8_t*>(&A_lds[w * 16 + l15][ks * 32 + 8 * lg]);
            #pragma unroll
            for (int kn = 0; kn < 4; ++kn) {
                bf16x8_t b = *reinterpret_cast<const bf16x8_t*>(&B_lds[kn * 16 + l15][ks * 32 + 8 * lg]);
                acc[kn] = __builtin_amdgcn_mfma_f32_16x16x32_bf16(a, b, acc[kn], 0, 0, 0);
            }
        }
    }

    #pragma unroll
    for (int kn = 0; kn < 4; ++kn) {
        const int col = kn * 16 + l15;
        const float bb = bias[col];
        #pragma unroll
        for (int j = 0; j < 4; ++j) {
            const int grow = g0 + w * 16 + lg * 4 + j;
            const u16 val = to_bf(acc[kn][j] + bb);
            if (z == 0) {
                outQ[(size_t)grow * HD + col] = val;
            } else if (z == 1) {
                outK[(size_t)grow * HD + col] = val;
            } else {
                const int b = grow >> 12, s = grow & (SEQ - 1);
                outVT[((size_t)(b * HD + col)) * SEQ + s] = val;
            }
        }
    }
}

// ---------------------------------------------------------------------------
// Split-K flash attention partials. Fixed m=0 softmax -> partial (o, lsum)
// over a key chunk is LINEAR, so chunks just add in the reduce kernel.
// Grid (8, 36, 4): x -> 4 q-tiles (one per wave), y -> (group g, chunk c),
// z -> batch. Group g = tq>>5 has nc = g+1 chunks per tile; all 4 waves of
// a block share identical key streams (same nt, same chunk bounds).
// Each wave: <= 8 key-tiles, register ping-pong prefetch, barrier-free.
// ---------------------------------------------------------------------------
__global__ __launch_bounds__(256, 4)
void attn_part_kernel(const u16* __restrict__ Q, const u16* __restrict__ K,
                      const u16* __restrict__ VT, float* __restrict__ partials)
{
    const int tid  = threadIdx.x;
    const int lane = tid & 63;
    const int w    = tid >> 6;
    const int l15  = lane & 15;
    const int lg   = lane >> 4;

    const int b = blockIdx.z;
    const int y = blockIdx.y;              // 0..35 -> (g, c)
    int g = 0;
    while ((g + 1) * (g + 2) / 2 <= y) ++g;      // g: triangular bucket of y
    const int c  = y - g * (g + 1) / 2;          // chunk index, 0..g
    const int nc = g + 1;
    const int tq = 32 * g + 4 * blockIdx.x + w;  // q-tile 0..255
    const int qbase = tq * 16;
    const int nt = (tq >> 2) + 1;                // key tiles for this q-tile
    const int t_start = (c * nt) / nc;
    const int t_end   = ((c + 1) * nt) / nc;

    __shared__ u16 P_lds[4][16][72];             // per-wave private P round-trip

    const u16* Kb  = K  + (size_t)b * SEQ * HD;
    const u16* VTb = VT + (size_t)b * HD * SEQ;

    bf16x8_t qf[2];
    #pragma unroll
    for (int ks = 0; ks < 2; ++ks)
        qf[ks] = *reinterpret_cast<const bf16x8_t*>(
            &Q[((size_t)(b * SEQ + qbase + l15)) * HD + ks * 32 + 8 * lg]);

    f32x4_t o[4];
    float lsum[4];
    #pragma unroll
    for (int i = 0; i < 4; ++i) {
        lsum[i] = 0.f;
        #pragma unroll
        for (int j = 0; j < 4; ++j) o[i][j] = 0.f;
    }

    bf16x8_t kA[8], vA[8], kB[8], vB[8];

    auto LOADT = [&](bf16x8_t* kf, bf16x8_t* vf, int kt) {
        const int k0 = kt * 64;
        #pragma unroll
        for (int kn = 0; kn < 4; ++kn)
            #pragma unroll
            for (int ks = 0; ks < 2; ++ks)
                kf[kn * 2 + ks] = *reinterpret_cast<const bf16x8_t*>(
                    &Kb[((size_t)(k0 + kn * 16 + l15)) * HD + ks * 32 + 8 * lg]);
        #pragma unroll
        for (int dn = 0; dn < 4; ++dn)
            #pragma unroll
            for (int ks = 0; ks < 2; ++ks)
                vf[dn * 2 + ks] = *reinterpret_cast<const bf16x8_t*>(
                    &VTb[((size_t)(dn * 16 + l15)) * SEQ + k0 + ks * 32 + 8 * lg]);
    };

    auto COMPUTE = [&](const bf16x8_t* kf, const bf16x8_t* vf, int kt, bool masked) {
        const int k0 = kt * 64;
        f32x4_t sf[4];
        #pragma unroll
        for (int i = 0; i < 4; ++i)
            #pragma unroll
            for (int j = 0; j < 4; ++j) sf[i][j] = 0.f;
        #pragma unroll
        for (int ks = 0; ks < 2; ++ks)
            #pragma unroll
            for (int kn = 0; kn < 4; ++kn)
                sf[kn] = __builtin_amdgcn_mfma_f32_16x16x32_bf16(qf[ks], kf[kn * 2 + ks], sf[kn], 0, 0, 0);
        #pragma unroll
        for (int kn = 0; kn < 4; ++kn) {
            #pragma unroll
            for (int j = 0; j < 4; ++j) {
                float p = exp2f(sf[kn][j] * C2);
                if (masked) {
                    const int col  = k0 + kn * 16 + l15;
                    const int rowq = qbase + lg * 4 + j;
                    p = (col <= rowq) ? p : 0.f;
                }
                lsum[j] += p;
                P_lds[w][lg * 4 + j][kn * 16 + l15] = to_bf(p);
            }
        }
        __builtin_amdgcn_sched_barrier(0);
        asm volatile("s_waitcnt lgkmcnt(0)" ::: "memory");
        __builtin_amdgcn_sched_barrier(0);
        #pragma unroll
        for (int ks = 0; ks < 2; ++ks) {
            bf16x8_t pa = *reinterpret_cast<const bf16x8_t*>(&P_lds[w][l15][ks * 32 + 8 * lg]);
            #pragma unroll
            for (int dn = 0; dn < 4; ++dn)
                o[dn] = __builtin_amdgcn_mfma_f32_16x16x32_bf16(pa, vf[dn * 2 + ks], o[dn], 0, 0, 0);
        }
    };

    int kt = t_start;
    LOADT(kA, vA, kt);
    while (true) {
        if (kt + 1 < t_end) LOADT(kB, vB, kt + 1);
        COMPUTE(kA, vA, kt, kt == nt - 1);
        ++kt; if (kt >= t_end) break;
        if (kt + 1 < t_end) LOADT(kA, vA, kt + 1);
        COMPUTE(kB, vB, kt, kt == nt - 1);
        ++kt; if (kt >= t_end) break;
    }

    // partial slot: per batch, groups laid out by triangular prefix
    const int slot = b * SLOTS_PER_B + 32 * (g * (g + 1) / 2) + (tq & 31) * nc + c;
    float* P = partials + (size_t)slot * SLOT_F;

    // o partial: [row][col] = [16][64]
    #pragma unroll
    for (int dn = 0; dn < 4; ++dn)
        #pragma unroll
        for (int j = 0; j < 4; ++j)
            P[(lg * 4 + j) * 64 + dn * 16 + l15] = o[dn][j];

    // lsum partial: reduce across the 16-lane group, store per row
    #pragma unroll
    for (int j = 0; j < 4; ++j) {
        float v = lsum[j];
        v += __shfl_xor(v, 1);
        v += __shfl_xor(v, 2);
        v += __shfl_xor(v, 4);
        v += __shfl_xor(v, 8);
        if (l15 == 0) P[1024 + lg * 4 + j] = v;
    }
}

// ---------------------------------------------------------------------------
// Reduce: sum partial (o, lsum) over chunks, divide, write out [B,S,64] f32.
// One block per q-tile; thread t handles 4 consecutive floats.
// ---------------------------------------------------------------------------
__global__ __launch_bounds__(256)
void reduce_kernel(const float* __restrict__ partials, float* __restrict__ out)
{
    const int x  = blockIdx.x;     // 0..1023
    const int b  = x >> 8;
    const int tq = x & 255;
    const int g  = tq >> 5;
    const int nc = g + 1;
    const int slot0 = b * SLOTS_PER_B + 32 * (g * (g + 1) / 2) + (tq & 31) * nc;

    const int t  = threadIdx.x;    // 0..255
    const int e0 = t * 4;          // element offset in the 16x64 tile
    const int r  = t >> 4;         // row 0..15

    f32x4_t acc; acc[0] = acc[1] = acc[2] = acc[3] = 0.f;
    float l = 0.f;
    for (int c = 0; c < nc; ++c) {
        const float* P = partials + (size_t)(slot0 + c) * SLOT_F;
        f32x4_t p = *reinterpret_cast<const f32x4_t*>(&P[e0]);
        acc[0] += p[0]; acc[1] += p[1]; acc[2] += p[2]; acc[3] += p[3];
        l += P[1024 + r];
    }
    const float inv = 1.f / l;
    f32x4_t res;
    res[0] = acc[0] * inv; res[1] = acc[1] * inv;
    res[2] = acc[2] * inv; res[3] = acc[3] * inv;
    *reinterpret_cast<f32x4_t*>(&out[((size_t)(b * SEQ) + tq * 16 + r) * HD + (t & 15) * 4]) = res;
}

extern "C" void kernel_launch(void* const* d_in, const int* in_sizes, int n_in,
                              void* d_out, int out_size, void* d_ws, size_t ws_size,
                              hipStream_t stream)
{
    const float* q_in = (const float*)d_in[0];
    const float* k_in = (const float*)d_in[1];
    const float* v_in = (const float*)d_in[2];
    const float* Wq   = (const float*)d_in[3];
    const float* bq   = (const float*)d_in[4];
    const float* Wk   = (const float*)d_in[5];
    const float* bk   = (const float*)d_in[6];
    const float* Wv   = (const float*)d_in[7];
    const float* bv   = (const float*)d_in[8];
    float* out = (float*)d_out;

    const size_t NQ = (size_t)NBATCH * SEQ * HD;   // 1M elements
    u16* wsQ  = (u16*)d_ws;
    u16* wsK  = wsQ + NQ;
    u16* wsVT = wsK + NQ;
    float* partials = (float*)((char*)d_ws + 3 * NQ * sizeof(u16));  // 19.2 MB

    proj_kernel<<<dim3(256, 3), 256, 0, stream>>>(q_in, k_in, v_in, Wq, bq, Wk, bk,
                                                  Wv, bv, wsQ, wsK, wsVT);
    attn_part_kernel<<<dim3(8, 36, NBATCH), 256, 0, stream>>>(wsQ, wsK, wsVT, partials);
    reduce_kernel<<<dim3(1024), 256, 0, stream>>>(partials, out);
}

// Round 4
// 105.534 us; speedup vs baseline: 1.8800x; 1.8800x over previous
//
#include <hip/hip_runtime.h>
#include <hip/hip_bf16.h>
#include <math.h>

typedef unsigned short u16;
typedef __attribute__((ext_vector_type(8))) short bf16x8_t;   // 8 bf16 in 4 VGPRs
typedef __attribute__((ext_vector_type(4))) float f32x4_t;
typedef __attribute__((ext_vector_type(4))) int  i32x4_t;

#define SEQ 4096
#define EMB 512
#define HD  64
#define NBATCH 4
// 1/sqrt(512) * log2(e)  (bug-faithful d_k = embed dim 512)
#define C2 0.063758718f

#define SLOT_F 1040           // floats per partial slot: 16*64 o + 16 lsum
#define SLOTS_PER_B 1152      // sum over tiles of chunk counts

__device__ __forceinline__ u16 to_bf(float f) {
    __hip_bfloat16 h = __float2bfloat16(f);
    return __builtin_bit_cast(u16, h);
}

// ---------------------------------------------------------------------------
// Projection: out[g][h] = sum_e in[g][e] * W[h][e] + b[h], g = 0..16383
// z = blockIdx.y: 0 -> Q, 1 -> K, 2 -> V (V written transposed [B][64][S])
// ---------------------------------------------------------------------------
__global__ __launch_bounds__(256)
void proj_kernel(const float* __restrict__ q_in, const float* __restrict__ k_in,
                 const float* __restrict__ v_in,
                 const float* __restrict__ Wq, const float* __restrict__ bq,
                 const float* __restrict__ Wk, const float* __restrict__ bk,
                 const float* __restrict__ Wv, const float* __restrict__ bv,
                 u16* __restrict__ outQ, u16* __restrict__ outK,
                 u16* __restrict__ outVT)
{
    const int z = blockIdx.y;
    const float* in   = (z == 0) ? q_in : (z == 1) ? k_in : v_in;
    const float* W    = (z == 0) ? Wq   : (z == 1) ? Wk   : Wv;
    const float* bias = (z == 0) ? bq   : (z == 1) ? bk   : bv;

    __shared__ u16 A_lds[64][72];
    __shared__ u16 B_lds[64][72];

    const int tid  = threadIdx.x;
    const int lane = tid & 63;
    const int w    = tid >> 6;
    const int l15  = lane & 15;
    const int lg   = lane >> 4;
    const int g0   = blockIdx.x * 64;

    f32x4_t acc[4];
    #pragma unroll
    for (int i = 0; i < 4; ++i)
        #pragma unroll
        for (int j = 0; j < 4; ++j) acc[i][j] = 0.f;

    const int r   = tid >> 2;
    const int seg = tid & 3;

    for (int ec = 0; ec < EMB / 64; ++ec) {
        __syncthreads();
        {
            const float* srcA = in + (size_t)(g0 + r) * EMB + ec * 64 + seg * 16;
            const float* srcB = W  + (size_t)r        * EMB + ec * 64 + seg * 16;
            u16 ta[16], tb[16];
            #pragma unroll
            for (int u = 0; u < 4; ++u) {
                f32x4_t fa = *reinterpret_cast<const f32x4_t*>(srcA + 4 * u);
                f32x4_t fb = *reinterpret_cast<const f32x4_t*>(srcB + 4 * u);
                #pragma unroll
                for (int q = 0; q < 4; ++q) {
                    ta[4 * u + q] = to_bf(fa[q]);
                    tb[4 * u + q] = to_bf(fb[q]);
                }
            }
            *reinterpret_cast<i32x4_t*>(&A_lds[r][seg * 16 + 0]) = *reinterpret_cast<i32x4_t*>(&ta[0]);
            *reinterpret_cast<i32x4_t*>(&A_lds[r][seg * 16 + 8]) = *reinterpret_cast<i32x4_t*>(&ta[8]);
            *reinterpret_cast<i32x4_t*>(&B_lds[r][seg * 16 + 0]) = *reinterpret_cast<i32x4_t*>(&tb[0]);
            *reinterpret_cast<i32x4_t*>(&B_lds[r][seg * 16 + 8]) = *reinterpret_cast<i32x4_t*>(&tb[8]);
        }
        __syncthreads();
        #pragma unroll
        for (int ks = 0; ks < 2; ++ks) {
            bf16x8_t a = *reinterpret_cast<const bf16x8_t*>(&A_lds[w * 16 + l15][ks * 32 + 8 * lg]);
            #pragma unroll
            for (int kn = 0; kn < 4; ++kn) {
                bf16x8_t b = *reinterpret_cast<const bf16x8_t*>(&B_lds[kn * 16 + l15][ks * 32 + 8 * lg]);
                acc[kn] = __builtin_amdgcn_mfma_f32_16x16x32_bf16(a, b, acc[kn], 0, 0, 0);
            }
        }
    }

    #pragma unroll
    for (int kn = 0; kn < 4; ++kn) {
        const int col = kn * 16 + l15;
        const float bb = bias[col];
        #pragma unroll
        for (int j = 0; j < 4; ++j) {
            const int grow = g0 + w * 16 + lg * 4 + j;
            const u16 val = to_bf(acc[kn][j] + bb);
            if (z == 0) {
                outQ[(size_t)grow * HD + col] = val;
            } else if (z == 1) {
                outK[(size_t)grow * HD + col] = val;
            } else {
                const int b = grow >> 12, s = grow & (SEQ - 1);
                outVT[((size_t)(b * HD + col)) * SEQ + s] = val;
            }
        }
    }
}

// ---------------------------------------------------------------------------
// Split-K flash attention partials. Fixed m=0 softmax -> partial (o, lsum)
// over a key chunk is LINEAR, so chunks just add in the reduce kernel.
// Grid (8, 36, 4): x -> 4 q-tiles (one per wave), y -> (group g, chunk c),
// z -> batch. Group g = tq>>5 has nc = g+1 chunks per tile; all 4 waves of
// a block share identical key streams (same nt, same chunk bounds).
// Each wave: <= 8 key-tiles, register ping-pong prefetch, barrier-free.
// NOTE: no occupancy clamp — R3's __launch_bounds__(256,4) capped VGPR at 64
// and spilled the fragment arrays to scratch (322 MB of writes). 112 VGPR
// natural -> 4 waves/SIMD without spilling.
// ---------------------------------------------------------------------------
__global__ __launch_bounds__(256)
void attn_part_kernel(const u16* __restrict__ Q, const u16* __restrict__ K,
                      const u16* __restrict__ VT, float* __restrict__ partials)
{
    const int tid  = threadIdx.x;
    const int lane = tid & 63;
    const int w    = tid >> 6;
    const int l15  = lane & 15;
    const int lg   = lane >> 4;

    const int b = blockIdx.z;
    const int y = blockIdx.y;              // 0..35 -> (g, c)
    int g = 0;
    while ((g + 1) * (g + 2) / 2 <= y) ++g;      // g: triangular bucket of y
    const int c  = y - g * (g + 1) / 2;          // chunk index, 0..g
    const int nc = g + 1;
    const int tq = 32 * g + 4 * blockIdx.x + w;  // q-tile 0..255
    const int qbase = tq * 16;
    const int nt = (tq >> 2) + 1;                // key tiles for this q-tile
    const int t_start = (c * nt) / nc;
    const int t_end   = ((c + 1) * nt) / nc;

    __shared__ u16 P_lds[4][16][72];             // per-wave private P round-trip

    const u16* Kb  = K  + (size_t)b * SEQ * HD;
    const u16* VTb = VT + (size_t)b * HD * SEQ;

    bf16x8_t qf[2];
    #pragma unroll
    for (int ks = 0; ks < 2; ++ks)
        qf[ks] = *reinterpret_cast<const bf16x8_t*>(
            &Q[((size_t)(b * SEQ + qbase + l15)) * HD + ks * 32 + 8 * lg]);

    f32x4_t o[4];
    float lsum[4];
    #pragma unroll
    for (int i = 0; i < 4; ++i) {
        lsum[i] = 0.f;
        #pragma unroll
        for (int j = 0; j < 4; ++j) o[i][j] = 0.f;
    }

    bf16x8_t kA[8], vA[8], kB[8], vB[8];

    auto LOADT = [&](bf16x8_t* kf, bf16x8_t* vf, int kt) {
        const int k0 = kt * 64;
        #pragma unroll
        for (int kn = 0; kn < 4; ++kn)
            #pragma unroll
            for (int ks = 0; ks < 2; ++ks)
                kf[kn * 2 + ks] = *reinterpret_cast<const bf16x8_t*>(
                    &Kb[((size_t)(k0 + kn * 16 + l15)) * HD + ks * 32 + 8 * lg]);
        #pragma unroll
        for (int dn = 0; dn < 4; ++dn)
            #pragma unroll
            for (int ks = 0; ks < 2; ++ks)
                vf[dn * 2 + ks] = *reinterpret_cast<const bf16x8_t*>(
                    &VTb[((size_t)(dn * 16 + l15)) * SEQ + k0 + ks * 32 + 8 * lg]);
    };

    auto COMPUTE = [&](const bf16x8_t* kf, const bf16x8_t* vf, int kt, bool masked) {
        const int k0 = kt * 64;
        f32x4_t sf[4];
        #pragma unroll
        for (int i = 0; i < 4; ++i)
            #pragma unroll
            for (int j = 0; j < 4; ++j) sf[i][j] = 0.f;
        #pragma unroll
        for (int ks = 0; ks < 2; ++ks)
            #pragma unroll
            for (int kn = 0; kn < 4; ++kn)
                sf[kn] = __builtin_amdgcn_mfma_f32_16x16x32_bf16(qf[ks], kf[kn * 2 + ks], sf[kn], 0, 0, 0);
        #pragma unroll
        for (int kn = 0; kn < 4; ++kn) {
            #pragma unroll
            for (int j = 0; j < 4; ++j) {
                float p = exp2f(sf[kn][j] * C2);
                if (masked) {
                    const int col  = k0 + kn * 16 + l15;
                    const int rowq = qbase + lg * 4 + j;
                    p = (col <= rowq) ? p : 0.f;
                }
                lsum[j] += p;
                P_lds[w][lg * 4 + j][kn * 16 + l15] = to_bf(p);
            }
        }
        __builtin_amdgcn_sched_barrier(0);
        asm volatile("s_waitcnt lgkmcnt(0)" ::: "memory");
        __builtin_amdgcn_sched_barrier(0);
        #pragma unroll
        for (int ks = 0; ks < 2; ++ks) {
            bf16x8_t pa = *reinterpret_cast<const bf16x8_t*>(&P_lds[w][l15][ks * 32 + 8 * lg]);
            #pragma unroll
            for (int dn = 0; dn < 4; ++dn)
                o[dn] = __builtin_amdgcn_mfma_f32_16x16x32_bf16(pa, vf[dn * 2 + ks], o[dn], 0, 0, 0);
        }
    };

    int kt = t_start;
    LOADT(kA, vA, kt);
    while (true) {
        if (kt + 1 < t_end) LOADT(kB, vB, kt + 1);
        COMPUTE(kA, vA, kt, kt == nt - 1);
        ++kt; if (kt >= t_end) break;
        if (kt + 1 < t_end) LOADT(kA, vA, kt + 1);
        COMPUTE(kB, vB, kt, kt == nt - 1);
        ++kt; if (kt >= t_end) break;
    }

    // partial slot: per batch, groups laid out by triangular prefix
    const int slot = b * SLOTS_PER_B + 32 * (g * (g + 1) / 2) + (tq & 31) * nc + c;
    float* P = partials + (size_t)slot * SLOT_F;

    // o partial: [row][col] = [16][64]
    #pragma unroll
    for (int dn = 0; dn < 4; ++dn)
        #pragma unroll
        for (int j = 0; j < 4; ++j)
            P[(lg * 4 + j) * 64 + dn * 16 + l15] = o[dn][j];

    // lsum partial: reduce across the 16-lane group, store per row
    #pragma unroll
    for (int j = 0; j < 4; ++j) {
        float v = lsum[j];
        v += __shfl_xor(v, 1);
        v += __shfl_xor(v, 2);
        v += __shfl_xor(v, 4);
        v += __shfl_xor(v, 8);
        if (l15 == 0) P[1024 + lg * 4 + j] = v;
    }
}

// ---------------------------------------------------------------------------
// Reduce: sum partial (o, lsum) over chunks, divide, write out [B,S,64] f32.
// One block per q-tile; thread t handles 4 consecutive floats.
// ---------------------------------------------------------------------------
__global__ __launch_bounds__(256)
void reduce_kernel(const float* __restrict__ partials, float* __restrict__ out)
{
    const int x  = blockIdx.x;     // 0..1023
    const int b  = x >> 8;
    const int tq = x & 255;
    const int g  = tq >> 5;
    const int nc = g + 1;
    const int slot0 = b * SLOTS_PER_B + 32 * (g * (g + 1) / 2) + (tq & 31) * nc;

    const int t  = threadIdx.x;    // 0..255
    const int e0 = t * 4;          // element offset in the 16x64 tile
    const int r  = t >> 4;         // row 0..15

    f32x4_t acc; acc[0] = acc[1] = acc[2] = acc[3] = 0.f;
    float l = 0.f;
    for (int c = 0; c < nc; ++c) {
        const float* P = partials + (size_t)(slot0 + c) * SLOT_F;
        f32x4_t p = *reinterpret_cast<const f32x4_t*>(&P[e0]);
        acc[0] += p[0]; acc[1] += p[1]; acc[2] += p[2]; acc[3] += p[3];
        l += P[1024 + r];
    }
    const float inv = 1.f / l;
    f32x4_t res;
    res[0] = acc[0] * inv; res[1] = acc[1] * inv;
    res[2] = acc[2] * inv; res[3] = acc[3] * inv;
    *reinterpret_cast<f32x4_t*>(&out[((size_t)(b * SEQ) + tq * 16 + r) * HD + (t & 15) * 4]) = res;
}

extern "C" void kernel_launch(void* const* d_in, const int* in_sizes, int n_in,
                              void* d_out, int out_size, void* d_ws, size_t ws_size,
                              hipStream_t stream)
{
    const float* q_in = (const float*)d_in[0];
    const float* k_in = (const float*)d_in[1];
    const float* v_in = (const float*)d_in[2];
    const float* Wq   = (const float*)d_in[3];
    const float* bq   = (const float*)d_in[4];
    const float* Wk   = (const float*)d_in[5];
    const float* bk   = (const float*)d_in[6];
    const float* Wv   = (const float*)d_in[7];
    const float* bv   = (const float*)d_in[8];
    float* out = (float*)d_out;

    const size_t NQ = (size_t)NBATCH * SEQ * HD;   // 1M elements
    u16* wsQ  = (u16*)d_ws;
    u16* wsK  = wsQ + NQ;
    u16* wsVT = wsK + NQ;
    float* partials = (float*)((char*)d_ws + 3 * NQ * sizeof(u16));  // 19.2 MB

    proj_kernel<<<dim3(256, 3), 256, 0, stream>>>(q_in, k_in, v_in, Wq, bq, Wk, bk,
                                                  Wv, bv, wsQ, wsK, wsVT);
    attn_part_kernel<<<dim3(8, 36, NBATCH), 256, 0, stream>>>(wsQ, wsK, wsVT, partials);
    reduce_kernel<<<dim3(1024), 256, 0, stream>>>(partials, out);
}

// Round 5
// 66.832 us; speedup vs baseline: 2.9687x; 1.5791x over previous
//
#include <hip/hip_runtime.h>
#include <hip/hip_bf16.h>
#include <math.h>

typedef unsigned short u16;
typedef unsigned int   u32;
typedef __attribute__((ext_vector_type(8)))  short bf16x8_t;
typedef __attribute__((ext_vector_type(4)))  float f32x4_t;
typedef __attribute__((ext_vector_type(16))) float f32x16_t;
typedef __attribute__((ext_vector_type(4)))  int   i32x4_t;
typedef __attribute__((ext_vector_type(2)))  u32   u32x2_t;

#define SEQ 4096
#define EMB 512
#define HD  64
#define NBATCH 4
// 1/sqrt(512) * log2(e)  (bug-faithful d_k = embed dim 512)
#define C2 0.063758718f

#define NPAIR 136                    // (g,c) pairs per batch: sum_{g=0..15}(g+1)
#define SLOTS (NBATCH * NPAIR * 8)   // 4352 wave-partial slots

__device__ __forceinline__ u16 to_bf(float f) {
    __hip_bfloat16 h = __float2bfloat16(f);
    return __builtin_bit_cast(u16, h);
}

__device__ __forceinline__ void stage16(const u16* g, u16* l) {
    __builtin_amdgcn_global_load_lds(
        (const __attribute__((address_space(1))) void*)g,
        (__attribute__((address_space(3))) void*)l, 16, 0, 0);
}

// ---------------------------------------------------------------------------
// Projection: out[g][h] = sum_e in[g][e] * W[h][e] + b[h] (unchanged from R4)
// z: 0 -> Q, 1 -> K, 2 -> V (V written transposed [B][64][S])
// ---------------------------------------------------------------------------
__global__ __launch_bounds__(256)
void proj_kernel(const float* __restrict__ q_in, const float* __restrict__ k_in,
                 const float* __restrict__ v_in,
                 const float* __restrict__ Wq, const float* __restrict__ bq,
                 const float* __restrict__ Wk, const float* __restrict__ bk,
                 const float* __restrict__ Wv, const float* __restrict__ bv,
                 u16* __restrict__ outQ, u16* __restrict__ outK,
                 u16* __restrict__ outVT)
{
    const int z = blockIdx.y;
    const float* in   = (z == 0) ? q_in : (z == 1) ? k_in : v_in;
    const float* W    = (z == 0) ? Wq   : (z == 1) ? Wk   : Wv;
    const float* bias = (z == 0) ? bq   : (z == 1) ? bk   : bv;

    __shared__ u16 A_lds[64][72];
    __shared__ u16 B_lds[64][72];

    const int tid  = threadIdx.x;
    const int lane = tid & 63;
    const int w    = tid >> 6;
    const int l15  = lane & 15;
    const int lg   = lane >> 4;
    const int g0   = blockIdx.x * 64;

    f32x4_t acc[4];
    #pragma unroll
    for (int i = 0; i < 4; ++i)
        #pragma unroll
        for (int j = 0; j < 4; ++j) acc[i][j] = 0.f;

    const int r   = tid >> 2;
    const int seg = tid & 3;

    for (int ec = 0; ec < EMB / 64; ++ec) {
        __syncthreads();
        {
            const float* srcA = in + (size_t)(g0 + r) * EMB + ec * 64 + seg * 16;
            const float* srcB = W  + (size_t)r        * EMB + ec * 64 + seg * 16;
            u16 ta[16], tb[16];
            #pragma unroll
            for (int u = 0; u < 4; ++u) {
                f32x4_t fa = *reinterpret_cast<const f32x4_t*>(srcA + 4 * u);
                f32x4_t fb = *reinterpret_cast<const f32x4_t*>(srcB + 4 * u);
                #pragma unroll
                for (int q = 0; q < 4; ++q) {
                    ta[4 * u + q] = to_bf(fa[q]);
                    tb[4 * u + q] = to_bf(fb[q]);
                }
            }
            *reinterpret_cast<i32x4_t*>(&A_lds[r][seg * 16 + 0]) = *reinterpret_cast<i32x4_t*>(&ta[0]);
            *reinterpret_cast<i32x4_t*>(&A_lds[r][seg * 16 + 8]) = *reinterpret_cast<i32x4_t*>(&ta[8]);
            *reinterpret_cast<i32x4_t*>(&B_lds[r][seg * 16 + 0]) = *reinterpret_cast<i32x4_t*>(&tb[0]);
            *reinterpret_cast<i32x4_t*>(&B_lds[r][seg * 16 + 8]) = *reinterpret_cast<i32x4_t*>(&tb[8]);
        }
        __syncthreads();
        #pragma unroll
        for (int ks = 0; ks < 2; ++ks) {
            bf16x8_t a = *reinterpret_cast<const bf16x8_t*>(&A_lds[w * 16 + l15][ks * 32 + 8 * lg]);
            #pragma unroll
            for (int kn = 0; kn < 4; ++kn) {
                bf16x8_t b = *reinterpret_cast<const bf16x8_t*>(&B_lds[kn * 16 + l15][ks * 32 + 8 * lg]);
                acc[kn] = __builtin_amdgcn_mfma_f32_16x16x32_bf16(a, b, acc[kn], 0, 0, 0);
            }
        }
    }

    #pragma unroll
    for (int kn = 0; kn < 4; ++kn) {
        const int col = kn * 16 + l15;
        const float bb = bias[col];
        #pragma unroll
        for (int j = 0; j < 4; ++j) {
            const int grow = g0 + w * 16 + lg * 4 + j;
            const u16 val = to_bf(acc[kn][j] + bb);
            if (z == 0) {
                outQ[(size_t)grow * HD + col] = val;
            } else if (z == 1) {
                outK[(size_t)grow * HD + col] = val;
            } else {
                const int b = grow >> 12, s = grow & (SEQ - 1);
                outVT[((size_t)(b * HD + col)) * SEQ + s] = val;
            }
        }
    }
}

// ---------------------------------------------------------------------------
// 8-wave flash attention (m214-style), split-K partials.
// Block = 8 waves x 32 q-rows = 256 rows; 64-key tiles staged ONCE per block
// into XOR-swizzled LDS via global_load_lds (pre-swizzled source).
// Swapped QK^T: mfma_32x32x16(A=K, B=Q) -> C[key][q], col=lane&31=q,
// row=key=(r&3)+8*(r>>2)+4*(lane>>5). Softmax m=0 (scores tiny). P^T packed
// to per-wave swizzled LDS (b64 writes), PV: mfma(A=VT, B=P^T) -> O^T[d][q].
// Chunks of 4 tiles -> 544 uniform blocks; partials are linear (m=0).
// ---------------------------------------------------------------------------
__global__ __launch_bounds__(512, 4)
void attn8_kernel(const u16* __restrict__ Q, const u16* __restrict__ K,
                  const u16* __restrict__ VT,
                  u16* __restrict__ partO, float* __restrict__ partL)
{
    __shared__ u16 Kt[2][64 * 64];   // [buf][key*64 + h], chunk-swizzled
    __shared__ u16 Vt[2][64 * 64];   // [buf][d*64 + key], chunk-swizzled
    __shared__ u16 Pt[8][32 * 64];   // per-wave P^T [q][key], swizzled

    const int tid  = threadIdx.x;
    const int w    = tid >> 6;
    const int lane = tid & 63;
    const int q31  = lane & 31;
    const int half = lane >> 5;

    const int b = blockIdx.y;
    const int y = blockIdx.x;                 // 0..135
    int g = 0;
    while ((g + 1) * (g + 2) / 2 <= y) ++g;
    const int c = y - g * (g + 1) / 2;        // chunk 0..g

    const int R0   = 256 * g + 32 * w;        // wave's first q row
    const int q_g  = R0 + q31;                // this lane's q row
    const int nt_w = 4 * g + (w >> 1) + 1;    // key tiles this wave needs
    const int t0   = 4 * c, t1 = 4 * c + 4;   // block-wide staged tile range

    const u16* Kb  = K  + (size_t)b * SEQ * HD;
    const u16* VTb = VT + (size_t)b * HD * SEQ;

    // staging geometry: wave w = instr index; lane covers 16B chunk
    const int srow = w * 8 + (lane >> 3);           // row within 64-row tile
    const int schk = (lane & 7) ^ ((lane >> 3) & 7); // pre-swizzled src chunk

    // Q fragments (B-operand): lane holds Q[q_g][s*16 + 8*half .. +7]
    bf16x8_t qf0, qf1, qf2, qf3;
    {
        const u16* qp = Q + ((size_t)b * SEQ + q_g) * HD + 8 * half;
        qf0 = *(const bf16x8_t*)(qp + 0);
        qf1 = *(const bf16x8_t*)(qp + 16);
        qf2 = *(const bf16x8_t*)(qp + 32);
        qf3 = *(const bf16x8_t*)(qp + 48);
    }

    f32x16_t acc0, acc1;
    #pragma unroll
    for (int i = 0; i < 16; ++i) { acc0[i] = 0.f; acc1[i] = 0.f; }
    float lsum = 0.f;

    auto STAGE = [&](int u, int t) {
        stage16(&Kb[((size_t)(t * 64 + srow)) * HD + schk * 8], &Kt[u][w * 512]);
        stage16(&VTb[(size_t)srow * SEQ + t * 64 + schk * 8],   &Vt[u][w * 512]);
    };

    STAGE(0, t0);
    asm volatile("s_waitcnt vmcnt(0)" ::: "memory");
    __syncthreads();

    for (int t = t0; t < t1; ++t) {
        const int u = (t - t0) & 1;
        if (t + 1 < t1) STAGE(u ^ 1, t + 1);
        if (t < nt_w) {
            const bool last = (t == nt_w - 1);
            // ---- QK^T (swapped) + softmax + packed P^T write, per 32-key subtile
            #pragma unroll
            for (int ksub = 0; ksub < 2; ++ksub) {
                f32x16_t sf;
                #pragma unroll
                for (int i = 0; i < 16; ++i) sf[i] = 0.f;
                const int kl = ksub * 32 + q31;     // A row = key (local)
                #pragma unroll
                for (int s = 0; s < 4; ++s) {
                    bf16x8_t a = *(const bf16x8_t*)
                        &Kt[u][kl * 64 + ((s * 16 + 8 * half) ^ ((kl & 7) << 3))];
                    bf16x8_t qq = (s == 0) ? qf0 : (s == 1) ? qf1 : (s == 2) ? qf2 : qf3;
                    sf = __builtin_amdgcn_mfma_f32_32x32x16_bf16(a, qq, sf, 0, 0, 0);
                }
                #pragma unroll
                for (int j = 0; j < 4; ++j) {
                    float p[4];
                    #pragma unroll
                    for (int e = 0; e < 4; ++e) {
                        const int kk    = 8 * j + 4 * half + e;          // key in subtile
                        const int key_g = t * 64 + ksub * 32 + kk;
                        float v = exp2f(sf[4 * j + e] * C2);
                        if (last && key_g > q_g) v = 0.f;
                        lsum += v;
                        p[e] = v;
                    }
                    u32x2_t pk;
                    pk[0] = (u32)to_bf(p[0]) | ((u32)to_bf(p[1]) << 16);
                    pk[1] = (u32)to_bf(p[2]) | ((u32)to_bf(p[3]) << 16);
                    const int col = (ksub * 32 + 8 * j + 4 * half) ^ ((q31 & 7) << 3);
                    *(u32x2_t*)&Pt[w][q31 * 64 + col] = pk;
                }
            }
            // own-wave LDS write->read fence (rule 18)
            asm volatile("s_waitcnt lgkmcnt(0)" ::: "memory");
            __builtin_amdgcn_sched_barrier(0);
            // ---- PV: O^T[d][q] += VT[d][key] * P^T[key][q]
            #pragma unroll
            for (int kp = 0; kp < 4; ++kp) {
                bf16x8_t pb = *(const bf16x8_t*)
                    &Pt[w][q31 * 64 + ((kp * 16 + 8 * half) ^ ((q31 & 7) << 3))];
                {
                    const int dl = q31;
                    bf16x8_t va = *(const bf16x8_t*)
                        &Vt[u][dl * 64 + ((kp * 16 + 8 * half) ^ ((dl & 7) << 3))];
                    acc0 = __builtin_amdgcn_mfma_f32_32x32x16_bf16(va, pb, acc0, 0, 0, 0);
                }
                {
                    const int dl = 32 + q31;
                    bf16x8_t va = *(const bf16x8_t*)
                        &Vt[u][dl * 64 + ((kp * 16 + 8 * half) ^ ((dl & 7) << 3))];
                    acc1 = __builtin_amdgcn_mfma_f32_32x32x16_bf16(va, pb, acc1, 0, 0, 0);
                }
            }
        }
        asm volatile("s_waitcnt vmcnt(0)" ::: "memory");
        __syncthreads();
    }

    // epilogue: combine lane halves' lsum, store bf16 O^T partial + f32 lsum
    lsum += __shfl_xor(lsum, 32);
    const int slot = (b * NPAIR + y) * 8 + w;
    u16* po = partO + (size_t)slot * 2048;
    #pragma unroll
    for (int dsub = 0; dsub < 2; ++dsub) {
        #pragma unroll
        for (int j = 0; j < 4; ++j) {
            const f32x16_t& a = dsub ? acc1 : acc0;   // compile-time select
            u32x2_t pk;
            pk[0] = (u32)to_bf(a[4 * j + 0]) | ((u32)to_bf(a[4 * j + 1]) << 16);
            pk[1] = (u32)to_bf(a[4 * j + 2]) | ((u32)to_bf(a[4 * j + 3]) << 16);
            const int d = 32 * dsub + 8 * j + 4 * half;
            *(u32x2_t*)&po[q31 * 64 + d] = pk;
        }
    }
    if (half == 0) partL[(size_t)slot * 32 + q31] = lsum;
}

// ---------------------------------------------------------------------------
// Reduce: sum bf16 O partials + lsum over chunks, divide, write f32 out.
// Block per (batch, g, wave): 512 blocks x 256 threads.
// ---------------------------------------------------------------------------
__global__ __launch_bounds__(256)
void reduce8_kernel(const u16* __restrict__ partO, const float* __restrict__ partL,
                    float* __restrict__ out)
{
    const int x  = blockIdx.x;          // 0..511
    const int b  = x >> 7;
    const int gw = x & 127;
    const int g  = gw >> 3;
    const int w  = gw & 7;
    const int ybase = g * (g + 1) / 2;

    const int t  = threadIdx.x;
    const int q  = t >> 3;              // 0..31
    const int d0 = (t & 7) * 8;         // 0,8,..,56

    float acc[8];
    #pragma unroll
    for (int i = 0; i < 8; ++i) acc[i] = 0.f;
    float l = 0.f;

    for (int c = 0; c <= g; ++c) {
        const int slot = (b * NPAIR + ybase + c) * 8 + w;
        i32x4_t raw = *(const i32x4_t*)(partO + (size_t)slot * 2048 + q * 64 + d0);
        const u16* pr = (const u16*)&raw;
        #pragma unroll
        for (int i = 0; i < 8; ++i) {
            u32 bits = ((u32)pr[i]) << 16;
            acc[i] += __builtin_bit_cast(float, bits);
        }
        l += partL[(size_t)slot * 32 + q];
    }
    const float inv = 1.f / l;
    f32x4_t r0, r1;
    #pragma unroll
    for (int i = 0; i < 4; ++i) { r0[i] = acc[i] * inv; r1[i] = acc[4 + i] * inv; }
    const size_t row = (size_t)b * SEQ + g * 256 + w * 32 + q;
    *(f32x4_t*)&out[row * HD + d0]     = r0;
    *(f32x4_t*)&out[row * HD + d0 + 4] = r1;
}

extern "C" void kernel_launch(void* const* d_in, const int* in_sizes, int n_in,
                              void* d_out, int out_size, void* d_ws, size_t ws_size,
                              hipStream_t stream)
{
    const float* q_in = (const float*)d_in[0];
    const float* k_in = (const float*)d_in[1];
    const float* v_in = (const float*)d_in[2];
    const float* Wq   = (const float*)d_in[3];
    const float* bq   = (const float*)d_in[4];
    const float* Wk   = (const float*)d_in[5];
    const float* bk   = (const float*)d_in[6];
    const float* Wv   = (const float*)d_in[7];
    const float* bv   = (const float*)d_in[8];
    float* out = (float*)d_out;

    const size_t NQ = (size_t)NBATCH * SEQ * HD;     // 1,048,576 elems
    u16* wsQ   = (u16*)d_ws;
    u16* wsK   = wsQ + NQ;
    u16* wsVT  = wsK + NQ;
    u16* partO = wsVT + NQ;                          // SLOTS*2048 u16 = 17.8 MB
    float* partL = (float*)(partO + (size_t)SLOTS * 2048);  // SLOTS*32 f32

    proj_kernel<<<dim3(256, 3), 256, 0, stream>>>(q_in, k_in, v_in, Wq, bq, Wk, bk,
                                                  Wv, bv, wsQ, wsK, wsVT);
    attn8_kernel<<<dim3(NPAIR, NBATCH), 512, 0, stream>>>(wsQ, wsK, wsVT, partO, partL);
    reduce8_kernel<<<dim3(512), 256, 0, stream>>>(partO, partL, out);
}